// Round 5
// baseline (1329.797 us; speedup 1.0000x reference)
//
#include <hip/hip_runtime.h>

// Autoregressive masked net sampler, restructured:
//  - output col i == sampling-time x[:,i]  (masks: out i depends on spins < i only)
//  - spin blocks of KB=8: history part = dense GEMM (MFMA f16, masks all-ones there),
//    intra-block part = sequential per-row (rows independent -> no grid sync)
// R4 lesson: 1024 one-wave WGs = 1 wave/SIMD -> latency-bound (VALUBusy 20%).
// R5: BT=8 (2048 WGs -> 2 waves/SIMD), layer-6 history offloaded to the MFMA gemm
// (y==4 slice), Zg init added at chain END (hides Zg load latency).

#define NS   64          // spins
#define HC   20          // hidden channels per spin
#define HTOT 1280        // NS*HC
#define NB   16384       // batch
#define KB   8           // spins per block (8 blocks)
#define BT   8           // batch rows per seq workgroup (single wave: 8 x 8)
#define W6R  80          // W6p padded rows (64 + 16 zero pad for MFMA tile)

typedef _Float16 f16;
typedef _Float16 f16x2 __attribute__((ext_vector_type(2)));
typedef _Float16 f16x8 __attribute__((ext_vector_type(8)));
typedef float f32x4 __attribute__((ext_vector_type(4)));

static __device__ __forceinline__ float dot2f(f16x2 a, f16x2 b, float c) {
#if __has_builtin(__builtin_amdgcn_fdot2)
  return __builtin_amdgcn_fdot2(a, b, c, false);
#else
  return c + (float)a[0] * (float)b[0] + (float)a[1] * (float)b[1];
#endif
}

static __device__ __forceinline__ float dot8f(f16x8 a, f16x8 b, float c) {
  f16x2 a0 = {a[0], a[1]}, a1 = {a[2], a[3]}, a2 = {a[4], a[5]}, a3 = {a[6], a[7]};
  f16x2 b0 = {b[0], b[1]}, b1 = {b[2], b[3]}, b2 = {b[4], b[5]}, b3 = {b[6], b[7]};
  c = dot2f(a0, b0, c);
  c = dot2f(a1, b1, c);
  c = dot2f(a2, b2, c);
  c = dot2f(a3, b3, c);
  return c;
}

static __device__ __forceinline__ float sigm(float z) {
  return __builtin_amdgcn_rcpf(1.0f + __expf(-z));
}

// ---------------------------------------------------------------------------
// prep: build masked, spin-major-permuted f16 weights.
//  Wp [L=0..3][cp][xp]  cp = j_out*20+ch_out, xp = j_in*20+ch_in, mask j_in <= j_out
//  W1p[cp][j_in]        mask j_in <  j_out  (exclusive)
//  W6p[i][xp]           mask j_in <= i  (rows 64..79 zero pad)
// ---------------------------------------------------------------------------
__global__ __launch_bounds__(256) void prep(
    const float* __restrict__ W1, const float* __restrict__ W2,
    const float* __restrict__ W3, const float* __restrict__ W4,
    const float* __restrict__ W5, const float* __restrict__ W6,
    f16* __restrict__ Wp, f16* __restrict__ W1p, f16* __restrict__ W6p) {
  __shared__ float row[HTOT];
  int bid = blockIdx.x;
  if (bid < 4 * HTOT) {
    int L = bid / HTOT, cp = bid % HTOT;
    int j_o = cp / HC, ch_o = cp % HC;
    const float* Wsrc = (L == 0) ? W2 : (L == 1) ? W3 : (L == 2) ? W4 : W5;
    const float* src = Wsrc + (size_t)(ch_o * NS + j_o) * HTOT;
    for (int k = threadIdx.x; k < HTOT; k += 256) row[k] = src[k];
    __syncthreads();
    f16* dst = Wp + (size_t)bid * HTOT;
    for (int xp = threadIdx.x; xp < HTOT; xp += 256) {
      int j_i = xp / HC, ch_i = xp % HC;
      float v = (j_i <= j_o) ? row[ch_i * NS + j_i] : 0.0f;
      dst[xp] = (f16)v;
    }
  } else if (bid < 4 * HTOT + 320) {
    int rr = (bid - 4 * HTOT) * 4 + (threadIdx.x >> 6);
    int c = threadIdx.x & 63;
    int j_o = rr / HC, ch_o = rr % HC;
    float v = (c < j_o) ? W1[(size_t)(ch_o * NS + j_o) * NS + c] : 0.0f;
    W1p[(size_t)rr * NS + c] = (f16)v;
  } else {
    int i = bid - (4 * HTOT + 320);
    if (i < NS) {
      const float* src = W6 + (size_t)i * HTOT;
      for (int k = threadIdx.x; k < HTOT; k += 256) row[k] = src[k];
      __syncthreads();
      for (int xp = threadIdx.x; xp < HTOT; xp += 256) {
        int j_i = xp / HC, ch_i = xp % HC;
        float v = (j_i <= i) ? row[ch_i * NS + j_i] : 0.0f;
        W6p[(size_t)i * HTOT + xp] = (f16)v;
      }
    } else {
      for (int xp = threadIdx.x; xp < HTOT; xp += 256)
        W6p[(size_t)i * HTOT + xp] = (f16)0.0f;
    }
  }
}

// ---------------------------------------------------------------------------
// gemm_block_mfma: history GEMMs for block starting at spin I.
//  y = L in 0..3:  Zg[L][c][b]  = sum_{k<20I} Wp[L][20I+c][k] * AH[L][k][b], c<160
//  y = 4 (layer6): Zg6[t][b]    = sum_{k<20I} W6p[I+t][k]    * AH[4][k][b], t<8
// MFMA f32_16x16x32_f16; AH [L][g=k/8][b][e=k%8] is the raw B-fragment layout.
// I==0: G32=0 -> writes zeros (initializes Zg/Zg6; d_ws is poisoned each call).
// ---------------------------------------------------------------------------
__global__ __launch_bounds__(256) void gemm_block_mfma(
    const f16* __restrict__ Wp, const f16* __restrict__ W6p,
    const f16* __restrict__ AH, float* __restrict__ Zg,
    float* __restrict__ Zg6, int I, int BS) {
  const int L = blockIdx.y;
  const int w = threadIdx.x >> 6;
  const int l15 = threadIdx.x & 15;
  const int quad = (threadIdx.x & 63) >> 4;
  const int G32 = (HC * I) >> 5;

  if (L < 4) {
    const int wm = w & 1, wn = w >> 1;
    const int b0 = blockIdx.x * 64 + wn * 32;

    f32x4 acc[5][2];
#pragma unroll
    for (int mt = 0; mt < 5; ++mt) {
      acc[mt][0] = (f32x4){0.f, 0.f, 0.f, 0.f};
      acc[mt][1] = (f32x4){0.f, 0.f, 0.f, 0.f};
    }

    const f16* aptr = Wp + (size_t)(L * HTOT + HC * I + wm * 80 + l15) * HTOT + quad * 8;
    const f16* bptr = AH + ((size_t)(L * 160 + quad) * BS + b0 + l15) * 8;

    for (int ks = 0; ks < G32; ++ks) {
      f16x8 bf0 = *(const f16x8*)(bptr);
      f16x8 bf1 = *(const f16x8*)(bptr + 128);
      f16x8 af[5];
#pragma unroll
      for (int mt = 0; mt < 5; ++mt)
        af[mt] = *(const f16x8*)(aptr + (size_t)(mt * 16) * HTOT);
#pragma unroll
      for (int mt = 0; mt < 5; ++mt) {
        acc[mt][0] = __builtin_amdgcn_mfma_f32_16x16x32_f16(af[mt], bf0, acc[mt][0], 0, 0, 0);
        acc[mt][1] = __builtin_amdgcn_mfma_f32_16x16x32_f16(af[mt], bf1, acc[mt][1], 0, 0, 0);
      }
      aptr += 32;
      bptr += (size_t)4 * BS * 8;
    }

#pragma unroll
    for (int mt = 0; mt < 5; ++mt)
#pragma unroll
      for (int nt = 0; nt < 2; ++nt)
#pragma unroll
        for (int r = 0; r < 4; ++r) {
          int c = wm * 80 + mt * 16 + quad * 4 + r;
          int b = b0 + nt * 16 + l15;
          Zg[(size_t)(L * 160 + c) * BS + b] = acc[mt][nt][r];
        }
  } else {
    // layer-6 slice: M=16 tile over W6p rows I..I+15 (rows 8..15 discarded)
    const int b0 = blockIdx.x * 64 + w * 16;
    f32x4 acc = (f32x4){0.f, 0.f, 0.f, 0.f};
    const f16* aptr = W6p + (size_t)(I + l15) * HTOT + quad * 8;
    const f16* bptr = AH + ((size_t)(4 * 160 + quad) * BS + b0 + l15) * 8;
    for (int ks = 0; ks < G32; ++ks) {
      f16x8 af = *(const f16x8*)(aptr);
      f16x8 bf = *(const f16x8*)(bptr);
      acc = __builtin_amdgcn_mfma_f32_16x16x32_f16(af, bf, acc, 0, 0, 0);
      aptr += 32;
      bptr += (size_t)4 * BS * 8;
    }
#pragma unroll
    for (int r = 0; r < 4; ++r) {
      int c = quad * 4 + r;
      if (c < 8) Zg6[(size_t)c * BS + b0 + l15] = acc[r];
    }
  }
}

// ---------------------------------------------------------------------------
// seq_block v4 (single-wave WG, BT=8): 64 threads = 8 rows x 8 channel-groups.
// group q<4 -> 3 channels (3q..3q+2); q>=4 -> 2 channels (12+2(q-4)..+1).
// __syncthreads in a 1-wave WG is just a waitcnt. LDS 14.6 KB. z6 history comes
// from Zg6 (gemm y=4); Zg/Zg6 added at the END of each dot chain (latency hiding).
// ---------------------------------------------------------------------------
__global__ __launch_bounds__(64) void seq_block(
    const f16* __restrict__ Wp, const f16* __restrict__ W1p,
    const f16* __restrict__ W6p, f16* __restrict__ AH,
    const float* __restrict__ Zg, const float* __restrict__ Zg6,
    f16* __restrict__ s_ws, const float* __restrict__ u,
    float* __restrict__ outp, int I, int BS, int b0) {
  __shared__ __align__(16) f16 aL[5][BT][168];   // 13440 B
  __shared__ __align__(16) f16 sL[BT][72];       // 1152 B  -> 14592 B total

  const int lane = threadIdx.x;
  const int r = lane & 7;
  const int q = lane >> 3;              // 0..7
  const int nch = (q < 4) ? 3 : 2;
  const int ch0 = (q < 4) ? 3 * q : 12 + 2 * (q - 4);
  const int brel = blockIdx.x * BT + r;
  const int bg = b0 + brel;

  // zero LDS activations / s (masked-weight tails must read as 0)
  {
    f16x8 z = {};
    f16x8* pa = (f16x8*)&aL[0][0][0];
    for (int k = lane; k < (5 * BT * 168) / 8; k += 64) pa[k] = z;
    f16x8* ps = (f16x8*)&sL[0][0];
    for (int k = lane; k < (BT * 72) / 8; k += 64) ps[k] = z;
  }
  __syncthreads();

  // load sampled-bit history j < I (I>>3 <= 7 chunks; group q loads chunk q)
  if (q < (I >> 3)) {
    f16x8 v = *(const f16x8*)(s_ws + (size_t)brel * NS + q * 8);
    *(f16x8*)&sL[r][q * 8] = v;
  }

  // layer-6 history from gemm: group q holds t=q's partial
  float z6r[KB];
#pragma unroll
  for (int t = 0; t < KB; ++t) z6r[t] = 0.0f;
  z6r[q] = Zg6[(size_t)q * BS + brel];
  __syncthreads();

  for (int t = 0; t < KB; ++t) {
    const int i = I + t;

    // ---- layer 1: gather over sampled bits ----
    {
      float acc[3] = {0, 0, 0};
      const int C1 = (i + 7) >> 3;
      for (int c8 = 0; c8 < C1; ++c8) {
        f16x8 sv = *(const f16x8*)&sL[r][c8 * 8];
#pragma unroll
        for (int k = 0; k < 3; ++k) {
          f16x8 w = *(const f16x8*)(W1p + (size_t)(i * HC + ch0 + k) * NS + c8 * 8);
          acc[k] = dot8f(sv, w, acc[k]);
        }
      }
#pragma unroll
      for (int k = 0; k < 3; ++k)
        if (k < nch) aL[0][r][t * HC + ch0 + k] = (f16)sigm(acc[k]);
    }
    __syncthreads();

    // ---- layers 2..5: intra-block gather; Zg(history) added at chain end ----
    const int C2 = (HC * (t + 1) + 7) >> 3;
    float a5r[3];
    for (int L = 0; L < 4; ++L) {
      float zin[3];
#pragma unroll
      for (int k = 0; k < 3; ++k)
        zin[k] = Zg[(size_t)(L * 160 + t * HC + ch0 + k) * BS + brel];
      float z[3] = {0, 0, 0};
      const f16* wrow = Wp + ((size_t)(L * HTOT + i * HC + ch0)) * HTOT + HC * I;
      for (int c8 = 0; c8 < C2; ++c8) {
        f16x8 av = *(const f16x8*)&aL[L][r][c8 * 8];
#pragma unroll
        for (int k = 0; k < 3; ++k) {
          f16x8 w = *(const f16x8*)(wrow + (size_t)k * HTOT + c8 * 8);
          z[k] = dot8f(av, w, z[k]);
        }
      }
#pragma unroll
      for (int k = 0; k < 3; ++k) {
        float a = sigm(zin[k] + z[k]);
        if (k < nch) aL[L + 1][r][t * HC + ch0 + k] = (f16)a;
        if (L == 3) a5r[k] = a;
      }
      __syncthreads();
    }

    // ---- scatter a5(spin i) into z6 partials for t' >= t ----
    for (int tp = t; tp < KB; ++tp) {
      float zz = z6r[tp];
#pragma unroll
      for (int k = 0; k < 3; ++k)
        if (k < nch)
          zz += (float)W6p[(size_t)(I + tp) * HTOT + i * HC + ch0 + k] * a5r[k];
      z6r[tp] = zz;
    }

    // ---- reduce z6 over 8 groups via shfl_xor; output + sample bit ----
    {
      float v = z6r[t];
      v += __shfl_xor(v, 8, 64);
      v += __shfl_xor(v, 16, 64);
      v += __shfl_xor(v, 32, 64);
      if (lane < BT) {
        float x = sigm(v);
        outp[(size_t)bg * NS + i] = x;  // final output col i == sampling-time x
        float uu = u[(size_t)i * NB + bg];
        sL[r][i] = (f16)((x >= uu) ? 1.0f : -1.0f);
      }
    }
    __syncthreads();
  }

  // ---- bulk writeout: block activations -> global AH ([L][g][b][e]), s bits ----
  for (int w = lane; w < 5 * 20 * BT; w += 64) {
    int rr = w & (BT - 1);
    int q8 = w >> 3;           // 0..99
    int L = q8 / 20, x8 = q8 % 20;
    f16x8 v = *(const f16x8*)&aL[L][rr][x8 * 8];
    int gg = ((HC * I) >> 3) + x8;
    *(f16x8*)(AH + ((size_t)(L * 160 + gg) * BS + blockIdx.x * BT + rr) * 8) = v;
  }
  if (lane < BT) {
    *(f16x8*)(s_ws + (size_t)(blockIdx.x * BT + lane) * NS + I) =
        *(const f16x8*)&sL[lane][I];
  }
}

// ---------------------------------------------------------------------------
extern "C" void kernel_launch(void* const* d_in, const int* in_sizes, int n_in,
                              void* d_out, int out_size, void* d_ws, size_t ws_size,
                              hipStream_t stream) {
  (void)in_sizes; (void)n_in; (void)out_size;
  const float* u  = (const float*)d_in[1];
  const float* W1 = (const float*)d_in[2];
  const float* W2 = (const float*)d_in[3];
  const float* W3 = (const float*)d_in[4];
  const float* W4 = (const float*)d_in[5];
  const float* W5 = (const float*)d_in[6];
  const float* W6 = (const float*)d_in[7];
  float* outp = (float*)d_out;

  const size_t wpEls  = (size_t)4 * HTOT * HTOT;   // 6,553,600
  const size_t w1Els  = (size_t)HTOT * NS;         // 81,920
  const size_t w6Els  = (size_t)W6R * HTOT;        // 102,400 (padded)
  const size_t wBytes = (wpEls + w1Els + w6Els) * sizeof(f16);
  // per-row: AH 5*160*8*2 + Zg 4*160*4 + Zg6 8*4 + s 64*2 = 15520 bytes
  size_t rem = (ws_size > wBytes + 4096) ? (ws_size - wBytes - 4096) : 0;
  long long bs = (long long)(rem / 15520);
  bs = (bs / 64) * 64;
  if (bs > NB) bs = NB;
  if (bs < 64) bs = 64;
  const int BS = (int)bs;

  f16* Wp  = (f16*)d_ws;
  f16* W1p = Wp + wpEls;
  f16* W6p = W1p + w1Els;
  f16* AH  = W6p + w6Els;                               // 5*160*BS*8 f16
  float* Zg  = (float*)(AH + (size_t)5 * 160 * BS * 8); // 4*160*BS f32
  float* Zg6 = Zg + (size_t)4 * 160 * BS;               // 8*BS f32
  f16* s_ws  = (f16*)(Zg6 + (size_t)8 * BS);            // BS*64 f16

  prep<<<dim3(4 * HTOT + 320 + W6R), dim3(256), 0, stream>>>(
      W1, W2, W3, W4, W5, W6, Wp, W1p, W6p);

  for (int c0 = 0; c0 < NB; c0 += BS) {
    int nr = NB - c0; if (nr > BS) nr = BS;
    for (int m = 0; m < NS / KB; ++m) {
      const int I = m * KB;
      gemm_block_mfma<<<dim3(nr / 64, 5), dim3(256), 0, stream>>>(
          Wp, W6p, AH, Zg, Zg6, I, BS);
      seq_block<<<dim3(nr / BT), dim3(64), 0, stream>>>(
          Wp, W1p, W6p, AH, Zg, Zg6, s_ws, u, outp, I, BS, c0);
    }
  }
}